// Round 10
// baseline (226.626 us; speedup 1.0000x reference)
//
#include <hip/hip_runtime.h>
#include <hip/hip_bf16.h>
#include <math.h>

#define BATCH  64
#define SEQ    2048
#define DMODEL 512
#define ATT    256
#define M_TOTAL (BATCH * SEQ)

#define MT     64                       // rows per block (fused kernel)
#define KC     32                       // k per chunk
#define NCHUNK 16
#define BCH    (ATT * KC)               // 8192 ushorts = 16 KB per B chunk half
#define WA_LO_OFF (NCHUNK * BCH)        // 131072 ushorts

#define NBLK   (M_TOTAL / MT)           // 2048 fused blocks
#define BPB    (SEQ / MT)               // 32 blocks per batch row

// d_ws layout: wa_cvt images | partial feat | partial (m,l) | per-batch (M,L)
#define PF_OFF  (1u << 20)                              // 4 MB: [2048][512] f32
#define ML_OFF  (PF_OFF + (size_t)NBLK * DMODEL * 4)    // 16 KB: [2048] float2
#define BS_OFF  (ML_OFF + (size_t)NBLK * 8)             // 512 B: [64] float2
#define WS_NEED (BS_OFF + (size_t)BATCH * 8)

typedef __attribute__((ext_vector_type(8))) short short8v;
typedef __attribute__((ext_vector_type(4))) float floatx4;

__device__ __forceinline__ ushort f2bf_rne(float f) {
    unsigned u = __float_as_uint(f);
    u += 0x7FFFu + ((u >> 16) & 1u);
    return (ushort)(u >> 16);
}
__device__ __forceinline__ float bf2f(ushort h) {
    return __uint_as_float(((unsigned)h) << 16);
}
__device__ __forceinline__ void gll16(const void* g, void* l) {
    __builtin_amdgcn_global_load_lds(
        (const __attribute__((address_space(1))) unsigned*)g,
        (__attribute__((address_space(3))) unsigned*)l, 16, 0, 0);
}
// sign-free fast tanh: 1 - 2/(e^{2x}+1); exact at +-inf, 0
__device__ __forceinline__ float fast_tanh(float x) {
    return 1.0f - 2.0f * __builtin_amdgcn_rcpf(__expf(x + x) + 1.0f);
}
// float4 -> packed bf16 hi (truncation) + lo (RNE of remainder)
__device__ __forceinline__ void cvt4(float4 v, uint2& hi, uint2& lo) {
    unsigned u0 = __float_as_uint(v.x), u1 = __float_as_uint(v.y);
    unsigned u2 = __float_as_uint(v.z), u3 = __float_as_uint(v.w);
    hi.x = __builtin_amdgcn_perm(u1, u0, 0x07060302u);   // [bf(y):bf(x)]
    hi.y = __builtin_amdgcn_perm(u3, u2, 0x07060302u);
    float r0 = v.x - __uint_as_float(u0 & 0xFFFF0000u);
    float r1 = v.y - __uint_as_float(u1 & 0xFFFF0000u);
    float r2 = v.z - __uint_as_float(u2 & 0xFFFF0000u);
    float r3 = v.w - __uint_as_float(u3 & 0xFFFF0000u);
    asm("v_cvt_pk_bf16_f32 %0, %1, %2" : "=v"(lo.x) : "v"(r0), "v"(r1));
    asm("v_cvt_pk_bf16_f32 %0, %1, %2" : "=v"(lo.y) : "v"(r2), "v"(r3));
}
// 8 floats -> hi/lo packed images (k-order preserved)
__device__ __forceinline__ void cvt8(float4 a, float4 b, uint4& hi, uint4& lo) {
    uint2 h0, l0, h1, l1;
    cvt4(a, h0, l0);
    cvt4(b, h1, l1);
    hi = make_uint4(h0.x, h0.y, h1.x, h1.y);
    lo = make_uint4(l0.x, l0.y, l1.x, l1.y);
}

// K0: Wa fp32 [256][512] -> bf16 hi/lo per-chunk quad-major images:
// elem (a, k): chunk kc=k>>5, quad q=(k&31)>>3 -> kc*8192 + (q*256+a)*8 + (k&7)
__global__ __launch_bounds__(256)
void wa_convert_kernel(const float* __restrict__ Wa, ushort* __restrict__ out) {
    int idx = blockIdx.x * 256 + threadIdx.x;   // 131072
    float x = Wa[idx];
    ushort hi = f2bf_rne(x);
    ushort lo = f2bf_rne(x - bf2f(hi));
    int a = idx >> 9, k = idx & 511;
    int kc = k >> 5, kk = k & 31, q = kk >> 3;
    size_t o = (size_t)kc * BCH + (size_t)(q * 256 + a) * 8 + (kk & 7);
    out[o] = hi;
    out[WA_LO_OFF + o] = lo;
}

// KF: fused scores + tanh-reduce + block-softmax + partial feature GEVM.
// 256 thr / 4 waves; 64 rows; wave wid owns cols [wid*64, +64).
// A direct from global (converted in regs); B single-buffered LDS (32 KB).
// 3 independent blocks/CU fill each other's staging stalls.
__global__ __launch_bounds__(256, 3)
void fused_kernel(const float* __restrict__ X,
                  const ushort* __restrict__ wa_cvt,
                  const float* __restrict__ ba,
                  const float* __restrict__ ae,
                  float* __restrict__ zg,
                  float* __restrict__ pfeat,
                  float2* __restrict__ pml) {
    __shared__ __align__(16) ushort bbuf[2 * BCH];   // 32 KB: [hi 16K | lo 16K]
    __shared__ float zb[4][MT];
    __shared__ float pbuf[MT];

    const int tid = threadIdx.x;
    const int l   = tid & 63;
    const int wid = tid >> 6;
    const int n   = l & 15, g = l >> 4;
    const int m0  = blockIdx.x * MT;

    // A source: lane row = m0 + mi*16 + n, k-window = kc*32 + g*8 .. +8
    const float* xb = X + (size_t)(m0 + n) * DMODEL + g * 8;
    // B frag offset in LDS chunk (quad-major): (g*256 + col)*8 ushorts
    const int bb = (g * 256 + wid * 64 + n) * 8;

    floatx4 acc[4][4];
    #pragma unroll
    for (int i = 0; i < 4; ++i)
        #pragma unroll
        for (int j = 0; j < 4; ++j)
            acc[i][j] = (floatx4){0.f, 0.f, 0.f, 0.f};

    float4 xr0[4], xr1[4];
    #pragma unroll
    for (int mi = 0; mi < 4; ++mi) {
        xr0[mi] = *(const float4*)(xb + (size_t)mi * 16 * DMODEL);
        xr1[mi] = *(const float4*)(xb + (size_t)mi * 16 * DMODEL + 4);
    }

    #pragma unroll 1
    for (int kc = 0; kc < NCHUNK; ++kc) {
        __syncthreads();                 // previous chunk's B reads done
        // stage B chunk: 32 segs x 1 KB (hi then lo), 8 gll/thread
        const char* ghi = (const char*)(wa_cvt + (size_t)kc * BCH);
        const char* glo = (const char*)(wa_cvt + (size_t)WA_LO_OFF + (size_t)kc * BCH);
        #pragma unroll
        for (int i = 0; i < 8; ++i) {
            int seg = wid * 8 + i;
            const char* src = (seg < 16 ? ghi + seg * 1024 : glo + (seg - 16) * 1024) + l * 16;
            gll16(src, (char*)bbuf + seg * 1024);
        }
        __syncthreads();                 // drains glls (compiler emits vmcnt 0)

        // convert this chunk's A fragments (regs already resident)
        short8v ah[4], av[4];
        #pragma unroll
        for (int mi = 0; mi < 4; ++mi)
            cvt8(xr0[mi], xr1[mi], *(uint4*)&ah[mi], *(uint4*)&av[mi]);

        // prefetch next chunk's A (completes during MFMAs)
        if (kc + 1 < NCHUNK) {
            #pragma unroll
            for (int mi = 0; mi < 4; ++mi) {
                xr0[mi] = *(const float4*)(xb + (size_t)mi * 16 * DMODEL + (kc + 1) * KC);
                xr1[mi] = *(const float4*)(xb + (size_t)mi * 16 * DMODEL + (kc + 1) * KC + 4);
            }
        }

        // 48 MFMAs
        #pragma unroll
        for (int nj = 0; nj < 4; ++nj) {
            short8v bh = *(const short8v*)&bbuf[bb + nj * 128];
            short8v bv = *(const short8v*)&bbuf[BCH + bb + nj * 128];
            #pragma unroll
            for (int mi = 0; mi < 4; ++mi) {
                acc[mi][nj] = __builtin_amdgcn_mfma_f32_16x16x32_bf16(av[mi], bh, acc[mi][nj], 0, 0, 0);
                acc[mi][nj] = __builtin_amdgcn_mfma_f32_16x16x32_bf16(ah[mi], bv, acc[mi][nj], 0, 0, 0);
                acc[mi][nj] = __builtin_amdgcn_mfma_f32_16x16x32_bf16(ah[mi], bh, acc[mi][nj], 0, 0, 0);
            }
        }
    }

    // ---- z epilogue (verified): row = mi*16 + g*4 + e, col = wid*64 + nj*16 + n
    float bav[4], aev[4];
    #pragma unroll
    for (int nj = 0; nj < 4; ++nj) {
        int c = wid * 64 + nj * 16 + n;
        bav[nj] = ba[c];
        aev[nj] = ae[c];
    }
    #pragma unroll
    for (int mi = 0; mi < 4; ++mi) {
        float zp[4] = {0.f, 0.f, 0.f, 0.f};
        #pragma unroll
        for (int nj = 0; nj < 4; ++nj)
            #pragma unroll
            for (int e = 0; e < 4; ++e)
                zp[e] += fast_tanh(acc[mi][nj][e] + bav[nj]) * aev[nj];
        #pragma unroll
        for (int off = 8; off >= 1; off >>= 1)
            #pragma unroll
            for (int e = 0; e < 4; ++e)
                zp[e] += __shfl_xor(zp[e], off, 64);
        if (n == 0)
            *(float4*)&zb[wid][mi * 16 + g * 4] = make_float4(zp[0], zp[1], zp[2], zp[3]);
    }
    __syncthreads();

    // ---- block softmax partials (wave 0 only; 64 rows)
    if (tid < MT) {
        float zsum = (zb[0][tid] + zb[1][tid]) + (zb[2][tid] + zb[3][tid]);
        zg[m0 + tid] = zsum;                         // raw z for weights pass
        float m = zsum;
        #pragma unroll
        for (int off = 32; off >= 1; off >>= 1)
            m = fmaxf(m, __shfl_xor(m, off, 64));
        float p = __expf(zsum - m);
        float lsum = p;
        #pragma unroll
        for (int off = 32; off >= 1; off >>= 1)
            lsum += __shfl_xor(lsum, off, 64);
        pbuf[tid] = p;
        if (tid == 0) pml[blockIdx.x] = make_float2(m, lsum);
    }
    __syncthreads();

    // ---- partial feature GEVM: pfeat[blk][f] = sum_s p[s] * X[m0+s][f]
    // thread tid covers f = tid and f = tid+256; X rows are L2-hot (just read).
    {
        float a0 = 0.f, a1 = 0.f;
        const float* xcol = X + (size_t)m0 * DMODEL + tid;
        #pragma unroll 8
        for (int s = 0; s < MT; ++s) {
            float ps = pbuf[s];
            a0 = fmaf(xcol[(size_t)s * DMODEL], ps, a0);
            a1 = fmaf(xcol[(size_t)s * DMODEL + 256], ps, a1);
        }
        pfeat[(size_t)blockIdx.x * DMODEL + tid]       = a0;
        pfeat[(size_t)blockIdx.x * DMODEL + tid + 256] = a1;
    }
}

// K-combine: per batch, merge 32 block partials with online-softmax rescale.
__global__ __launch_bounds__(512)
void combine_kernel(const float* __restrict__ pfeat, const float2* __restrict__ pml,
                    float* __restrict__ feat, float2* __restrict__ bstat) {
    const int b = blockIdx.x, tid = threadIdx.x;
    float M = -3.0e38f;
    #pragma unroll
    for (int c = 0; c < BPB; ++c)
        M = fmaxf(M, pml[b * BPB + c].x);
    float L = 0.f, s = 0.f;
    #pragma unroll 4
    for (int c = 0; c < BPB; ++c) {
        float2 ml = pml[b * BPB + c];
        float sc = __expf(ml.x - M);
        L += sc * ml.y;
        s = fmaf(sc, pfeat[(size_t)(b * BPB + c) * DMODEL + tid], s);
    }
    feat[(size_t)b * DMODEL + tid] = s / L;
    if (tid == 0) bstat[b] = make_float2(M, L);
}

// K-weights: w[b,s] = exp(z - M_b) / L_b, in place over zg.
__global__ __launch_bounds__(256)
void weights_kernel(float* __restrict__ zw, const float2* __restrict__ bstat) {
    int i = blockIdx.x * 256 + threadIdx.x;   // 131072
    float2 ml = bstat[i >> 11];               // SEQ = 2048
    zw[i] = __expf(zw[i] - ml.x) / ml.y;
}

extern "C" void kernel_launch(void* const* d_in, const int* in_sizes, int n_in,
                              void* d_out, int out_size, void* d_ws, size_t ws_size,
                              hipStream_t stream) {
    const float* X  = (const float*)d_in[0];
    const float* Wa = (const float*)d_in[1];
    const float* ba = (const float*)d_in[2];
    const float* ae = (const float*)d_in[3];
    float* out  = (float*)d_out;
    float* feat = out;                       // [64][512]
    float* wgt  = out + BATCH * DMODEL;      // [64][2048]; holds z then weights

    ushort* wa_cvt  = (ushort*)d_ws;                          // 512 KB
    float*  pfeat   = (float*)((char*)d_ws + PF_OFF);         // 4 MB
    float2* pml     = (float2*)((char*)d_ws + ML_OFF);        // 16 KB
    float2* bstat   = (float2*)((char*)d_ws + BS_OFF);        // 512 B

    wa_convert_kernel<<<ATT * DMODEL / 256, 256, 0, stream>>>(Wa, wa_cvt);
    fused_kernel<<<NBLK, 256, 0, stream>>>(X, wa_cvt, ba, ae, wgt, pfeat, pml);
    combine_kernel<<<BATCH, 512, 0, stream>>>(pfeat, pml, feat, bstat);
    weights_kernel<<<M_TOTAL / 256, 256, 0, stream>>>(wgt, bstat);
}

// Round 11
// 133.757 us; speedup vs baseline: 1.6943x; 1.6943x over previous
//
#include <hip/hip_runtime.h>
#include <hip/hip_bf16.h>
#include <math.h>

#define BATCH  64
#define SEQ    2048
#define DMODEL 512
#define ATT    256
#define M_TOTAL (BATCH * SEQ)

#define MT     128                      // rows per block
#define KC     32                       // k per chunk
#define NCHUNK 16
#define BCH    (ATT * KC)               // 8192 ushorts = 16 KB per B chunk half
#define WA_LO_OFF (NCHUNK * BCH)        // 131072 ushorts

#define NBLK   (M_TOTAL / MT)           // 1024 fused blocks
#define BPB    (SEQ / MT)               // 16 blocks per batch row

// d_ws layout
#define PF_OFF  (1u << 20)                              // 2 MB: [1024][512] f32
#define ML_OFF  (PF_OFF + (size_t)NBLK * DMODEL * 4)    // 8 KB: [1024] float2
#define BS_OFF  (ML_OFF + (size_t)NBLK * 8)             // 512 B: [64] float2

typedef __attribute__((ext_vector_type(8))) short short8v;
typedef __attribute__((ext_vector_type(4))) float floatx4;

__device__ __forceinline__ ushort f2bf_rne(float f) {
    unsigned u = __float_as_uint(f);
    u += 0x7FFFu + ((u >> 16) & 1u);
    return (ushort)(u >> 16);
}
__device__ __forceinline__ float bf2f(ushort h) {
    return __uint_as_float(((unsigned)h) << 16);
}
__device__ __forceinline__ void gll16(const void* g, void* l) {
    __builtin_amdgcn_global_load_lds(
        (const __attribute__((address_space(1))) unsigned*)g,
        (__attribute__((address_space(3))) unsigned*)l, 16, 0, 0);
}
// sign-free fast tanh: 1 - 2/(e^{2x}+1); exact at +-inf, 0
__device__ __forceinline__ float fast_tanh(float x) {
    return 1.0f - 2.0f * __builtin_amdgcn_rcpf(__expf(x + x) + 1.0f);
}
// float4 -> packed bf16 hi (truncation) + lo (RNE of remainder)
__device__ __forceinline__ void cvt4(float4 v, uint2& hi, uint2& lo) {
    unsigned u0 = __float_as_uint(v.x), u1 = __float_as_uint(v.y);
    unsigned u2 = __float_as_uint(v.z), u3 = __float_as_uint(v.w);
    hi.x = __builtin_amdgcn_perm(u1, u0, 0x07060302u);   // [bf(y):bf(x)]
    hi.y = __builtin_amdgcn_perm(u3, u2, 0x07060302u);
    float r0 = v.x - __uint_as_float(u0 & 0xFFFF0000u);
    float r1 = v.y - __uint_as_float(u1 & 0xFFFF0000u);
    float r2 = v.z - __uint_as_float(u2 & 0xFFFF0000u);
    float r3 = v.w - __uint_as_float(u3 & 0xFFFF0000u);
    asm("v_cvt_pk_bf16_f32 %0, %1, %2" : "=v"(lo.x) : "v"(r0), "v"(r1));
    asm("v_cvt_pk_bf16_f32 %0, %1, %2" : "=v"(lo.y) : "v"(r2), "v"(r3));
}
// 8 floats -> hi/lo packed images (k-order preserved)
__device__ __forceinline__ void cvt8(float4 a, float4 b, uint4& hi, uint4& lo) {
    uint2 h0, l0, h1, l1;
    cvt4(a, h0, l0);
    cvt4(b, h1, l1);
    hi = make_uint4(h0.x, h0.y, h1.x, h1.y);
    lo = make_uint4(l0.x, l0.y, l1.x, l1.y);
}

// K0: Wa fp32 [256][512] -> bf16 hi/lo per-chunk quad-major images:
// elem (a, k): chunk kc=k>>5, quad q=(k&31)>>3 -> kc*8192 + (q*256+a)*8 + (k&7)
__global__ __launch_bounds__(256)
void wa_convert_kernel(const float* __restrict__ Wa, ushort* __restrict__ out) {
    int idx = blockIdx.x * 256 + threadIdx.x;   // 131072
    float x = Wa[idx];
    ushort hi = f2bf_rne(x);
    ushort lo = f2bf_rne(x - bf2f(hi));
    int a = idx >> 9, k = idx & 511;
    int kc = k >> 5, kk = k & 31, q = kk >> 3;
    size_t o = (size_t)kc * BCH + (size_t)(q * 256 + a) * 8 + (kk & 7);
    out[o] = hi;
    out[WA_LO_OFF + o] = lo;
}

// KF: fused scores GEMM + tanh-reduce + block softmax + partial GEVM.
// 512 thr / 8 waves; tile 128 rows x 256 cols; wave (wm=wid>>1, wn=wid&1)
// owns rows [wm*32,+32) x cols [wn*128,+128); acc = 2x8 x f32x4 = 64 VGPR.
// A staged fp32 via gll (quad-XOR pre-swizzled source); B hi/lo via gll.
// 50.7 KB LDS, <=128 VGPR -> 2 independent blocks/CU break barrier lockstep.
__global__ __launch_bounds__(512, 4)
void fused_kernel(const float* __restrict__ X,
                  const ushort* __restrict__ wa_cvt,
                  const float* __restrict__ ba,
                  const float* __restrict__ ae,
                  float* __restrict__ zg,
                  float* __restrict__ pfeat,
                  float2* __restrict__ pml) {
    __shared__ __align__(16) float  afp[MT * KC];      // 16 KB fp32 A (swizzled)
    __shared__ __align__(16) ushort bbuf[2 * BCH];     // 32 KB: hi 16K | lo 16K
    __shared__ float zb[2][MT];
    __shared__ float pbuf[MT];
    __shared__ float redm[2], redl[2];

    const int tid = threadIdx.x;
    const int l   = tid & 63;
    const int wid = tid >> 6;
    const int wm  = wid >> 1, wn = wid & 1;
    const int n   = l & 15, g = l >> 4;
    const int m0  = blockIdx.x * MT;

    // A gll sources: slot s = seg*64 + l; row=s>>3, qp=(s>>1)&3, half=s&1;
    // logical quad at phys qp is qp^(row&3)  (per-instr: 8 rows x 128B lines)
    const float* asrc[2];
    {
        #pragma unroll
        for (int j = 0; j < 2; ++j) {
            int s = (wid * 2 + j) * 64 + l;
            int row = s >> 3, qp = (s >> 1) & 3, half = s & 1;
            asrc[j] = X + (size_t)(m0 + row) * DMODEL
                        + ((qp ^ (row & 3)) << 3) + (half << 2);
        }
    }
    // B frag base (quad-major): (g*256 + col)*8 ushorts, col = wn*128 + nj*16 + n
    const int bb = (g * 256 + wn * 128 + n) * 8;
    // A frag base: byte addr row*128 + (g^(row&3))*32, row = wm*32 + mi*16 + n
    const char* afrag[2];
    #pragma unroll
    for (int mi = 0; mi < 2; ++mi) {
        int ar = wm * 32 + mi * 16 + n;
        afrag[mi] = (const char*)afp + ar * 128 + ((g ^ (ar & 3)) << 5);
    }

    floatx4 acc[2][8];
    #pragma unroll
    for (int i = 0; i < 2; ++i)
        #pragma unroll
        for (int j = 0; j < 8; ++j)
            acc[i][j] = (floatx4){0.f, 0.f, 0.f, 0.f};

    #pragma unroll 1
    for (int kc = 0; kc < NCHUNK; ++kc) {
        __syncthreads();                 // previous chunk's LDS reads done
        // stage A: 2 gll/thread from swizzled X source
        #pragma unroll
        for (int j = 0; j < 2; ++j)
            gll16(asrc[j] + kc * KC, (char*)afp + (wid * 2 + j) * 1024);
        // stage B: 4 gll/thread from prebuilt chunk images
        const char* ghi = (const char*)(wa_cvt + (size_t)kc * BCH);
        const char* glo = (const char*)(wa_cvt + (size_t)WA_LO_OFF + (size_t)kc * BCH);
        #pragma unroll
        for (int i = 0; i < 4; ++i) {
            int seg = wid * 4 + i;       // 0..31: first 16 -> hi, rest -> lo
            const char* src = (seg < 16 ? ghi + seg * 1024
                                        : glo + (seg - 16) * 1024) + l * 16;
            gll16(src, (char*)bbuf + seg * 1024);
        }
        __syncthreads();                 // drains glls (compiler vmcnt 0)

        // A fragments: fp32 from LDS -> hi/lo bf16 in regs (hidden under MFMA)
        short8v ah[2], av[2];
        #pragma unroll
        for (int mi = 0; mi < 2; ++mi) {
            float4 f0 = *(const float4*)(afrag[mi]);
            float4 f1 = *(const float4*)(afrag[mi] + 16);
            cvt8(f0, f1, *(uint4*)&ah[mi], *(uint4*)&av[mi]);
        }
        // 48 MFMAs per wave
        #pragma unroll
        for (int nj = 0; nj < 8; ++nj) {
            short8v bh = *(const short8v*)&bbuf[bb + nj * 128];
            short8v bv = *(const short8v*)&bbuf[BCH + bb + nj * 128];
            #pragma unroll
            for (int mi = 0; mi < 2; ++mi) {
                acc[mi][nj] = __builtin_amdgcn_mfma_f32_16x16x32_bf16(av[mi], bh, acc[mi][nj], 0, 0, 0);
                acc[mi][nj] = __builtin_amdgcn_mfma_f32_16x16x32_bf16(ah[mi], bv, acc[mi][nj], 0, 0, 0);
                acc[mi][nj] = __builtin_amdgcn_mfma_f32_16x16x32_bf16(ah[mi], bh, acc[mi][nj], 0, 0, 0);
            }
        }
    }

    // ---- z epilogue: row = wm*32 + mi*16 + g*4 + e, col = wn*128 + nj*16 + n
    float bav[8], aev[8];
    #pragma unroll
    for (int nj = 0; nj < 8; ++nj) {
        int c = wn * 128 + nj * 16 + n;
        bav[nj] = ba[c];
        aev[nj] = ae[c];
    }
    #pragma unroll
    for (int mi = 0; mi < 2; ++mi) {
        float zp[4] = {0.f, 0.f, 0.f, 0.f};
        #pragma unroll
        for (int nj = 0; nj < 8; ++nj)
            #pragma unroll
            for (int e = 0; e < 4; ++e)
                zp[e] += fast_tanh(acc[mi][nj][e] + bav[nj]) * aev[nj];
        #pragma unroll
        for (int off = 8; off >= 1; off >>= 1)
            #pragma unroll
            for (int e = 0; e < 4; ++e)
                zp[e] += __shfl_xor(zp[e], off, 64);
        if (n == 0)
            *(float4*)&zb[wn][wm * 32 + mi * 16 + g * 4] =
                make_float4(zp[0], zp[1], zp[2], zp[3]);
    }
    __syncthreads();

    // ---- block softmax partials over 128 rows (waves 0-1)
    float zsum = 0.f, M = 0.f;
    if (tid < MT) {
        zsum = zb[0][tid] + zb[1][tid];
        zg[m0 + tid] = zsum;
        float mloc = zsum;
        #pragma unroll
        for (int off = 32; off >= 1; off >>= 1)
            mloc = fmaxf(mloc, __shfl_xor(mloc, off, 64));
        if (l == 0) redm[wid] = mloc;
    }
    __syncthreads();
    if (tid < MT) {
        M = fmaxf(redm[0], redm[1]);
        float p = __expf(zsum - M);
        pbuf[tid] = p;
        float s = p;
        #pragma unroll
        for (int off = 32; off >= 1; off >>= 1)
            s += __shfl_xor(s, off, 64);
        if (l == 0) redl[wid] = s;
    }
    __syncthreads();
    if (tid == 0)
        pml[blockIdx.x] = make_float2(fmaxf(redm[0], redm[1]), redl[0] + redl[1]);

    // ---- partial feature GEVM: pfeat[blk][f] = sum_s p[s]*X[m0+s][f]
    // X rows are L2/L3-hot (just streamed by this block).
    {
        float a0 = 0.f, a1 = 0.f, a2 = 0.f, a3 = 0.f;
        const float* xc = X + (size_t)m0 * DMODEL + tid;
        #pragma unroll 8
        for (int s = 0; s < MT; s += 4) {
            a0 = fmaf(xc[(size_t)(s + 0) * DMODEL], pbuf[s + 0], a0);
            a1 = fmaf(xc[(size_t)(s + 1) * DMODEL], pbuf[s + 1], a1);
            a2 = fmaf(xc[(size_t)(s + 2) * DMODEL], pbuf[s + 2], a2);
            a3 = fmaf(xc[(size_t)(s + 3) * DMODEL], pbuf[s + 3], a3);
        }
        pfeat[(size_t)blockIdx.x * DMODEL + tid] = (a0 + a1) + (a2 + a3);
    }
}

// K-combine: per batch, merge 16 block partials with online-softmax rescale.
__global__ __launch_bounds__(512)
void combine_kernel(const float* __restrict__ pfeat, const float2* __restrict__ pml,
                    float* __restrict__ feat, float2* __restrict__ bstat) {
    const int b = blockIdx.x, tid = threadIdx.x;
    float M = -3.0e38f;
    #pragma unroll
    for (int c = 0; c < BPB; ++c)
        M = fmaxf(M, pml[b * BPB + c].x);
    float L = 0.f, s = 0.f;
    #pragma unroll 4
    for (int c = 0; c < BPB; ++c) {
        float2 ml = pml[b * BPB + c];
        float sc = __expf(ml.x - M);
        L += sc * ml.y;
        s = fmaf(sc, pfeat[(size_t)(b * BPB + c) * DMODEL + tid], s);
    }
    feat[(size_t)b * DMODEL + tid] = s / L;
    if (tid == 0) bstat[b] = make_float2(M, L);
}

// K-weights: w[b,s] = exp(z - M_b) / L_b, in place over zg.
__global__ __launch_bounds__(256)
void weights_kernel(float* __restrict__ zw, const float2* __restrict__ bstat) {
    int i = blockIdx.x * 256 + threadIdx.x;   // 131072
    float2 ml = bstat[i >> 11];               // SEQ = 2048
    zw[i] = __expf(zw[i] - ml.x) / ml.y;
}

extern "C" void kernel_launch(void* const* d_in, const int* in_sizes, int n_in,
                              void* d_out, int out_size, void* d_ws, size_t ws_size,
                              hipStream_t stream) {
    const float* X  = (const float*)d_in[0];
    const float* Wa = (const float*)d_in[1];
    const float* ba = (const float*)d_in[2];
    const float* ae = (const float*)d_in[3];
    float* out  = (float*)d_out;
    float* feat = out;                       // [64][512]
    float* wgt  = out + BATCH * DMODEL;      // [64][2048]; holds z then weights

    ushort* wa_cvt  = (ushort*)d_ws;                          // 512 KB
    float*  pfeat   = (float*)((char*)d_ws + PF_OFF);         // 2 MB
    float2* pml     = (float2*)((char*)d_ws + ML_OFF);        // 8 KB
    float2* bstat   = (float2*)((char*)d_ws + BS_OFF);        // 512 B

    wa_convert_kernel<<<ATT * DMODEL / 256, 256, 0, stream>>>(Wa, wa_cvt);
    fused_kernel<<<NBLK, 512, 0, stream>>>(X, wa_cvt, ba, ae, wgt, pfeat, pml);
    combine_kernel<<<BATCH, 512, 0, stream>>>(pfeat, pml, feat, bstat);
    weights_kernel<<<M_TOTAL / 256, 256, 0, stream>>>(wgt, bstat);
}